// Round 1
// baseline (8779.031 us; speedup 1.0000x reference)
//
#include <hip/hip_runtime.h>

#define KP   2176   // padded K: 2048 h + 69 x + pad
#define H    2048
#define MB   512    // batch
#define IN   69
#define TGT  50

typedef unsigned short ushort_t;
typedef __attribute__((ext_vector_type(8))) short  short8;
typedef __attribute__((ext_vector_type(4))) float  float4_t;

__device__ __forceinline__ ushort_t f2bf(float f) {
  union { float f; unsigned u; } v; v.f = f;
  unsigned u = v.u;
  return (ushort_t)((u + 0x7fffu + ((u >> 16) & 1u)) >> 16);
}

__device__ __forceinline__ void gload_lds16(const void* g, void* l) {
  __builtin_amdgcn_global_load_lds((const __attribute__((address_space(1))) void*)g,
                                   (__attribute__((address_space(3))) void*)l, 16, 0, 0);
}

// ---------------- prep kernels ----------------

// W_big[8192][KP] bf16. GEMM col n -> (c, g): blk=n>>8, g=(n>>6)&3, c=blk*64+(n&63)
// g0: r rows   = [W_hh[c]        | W_ih[c]        | 0]
// g1: z rows   = [W_hh[2048+c]   | W_ih[2048+c]   | 0]
// g2: gh_n     = [W_hh[4096+c]   | 0              | 0]   (accumulated only for k<2048)
// g3: gi_n     = [0              | W_ih[4096+c]   | 0]   (accumulated only for k>=2048)
__global__ void build_wbig(const float* __restrict__ Whh, const float* __restrict__ Wih,
                           ushort_t* __restrict__ Wbig) {
  int k = blockIdx.x * 256 + threadIdx.x;
  int n = blockIdx.y;
  if (k >= KP) return;
  int g = (n >> 6) & 3;
  int c = ((n >> 8) << 6) | (n & 63);
  float v = 0.f;
  if (g <= 1) {
    int gr = g * H + c;
    if (k < H) v = Whh[(size_t)gr * H + k];
    else if (k < H + IN) v = Wih[(size_t)gr * IN + (k - H)];
  } else if (g == 2) {
    int gr = 2 * H + c;
    if (k < H) v = Whh[(size_t)gr * H + k];
  } else {
    int gr = 2 * H + c;
    if (k >= H && k < H + IN) v = Wih[(size_t)gr * IN + (k - H)];
  }
  Wbig[(size_t)n * KP + k] = f2bf(v);
}

__global__ void zero_u4(uint4* p, int n) {
  int i = blockIdx.x * 256 + threadIdx.x;
  if (i < n) p[i] = make_uint4(0, 0, 0, 0);
}

__global__ void fill_x0(const float* __restrict__ enc, ushort_t* __restrict__ Acat0) {
  int i = blockIdx.x * 256 + threadIdx.x;  // exactly 512*69 threads
  int b = i / IN, j = i - b * IN;
  Acat0[(size_t)b * KP + H + j] = f2bf(enc[(size_t)b * 100 * IN + j]);
}

__global__ void build_fc1(const float* __restrict__ fc1w, ushort_t* __restrict__ fc1b16) {
  int k = blockIdx.x * 256 + threadIdx.x;  // 2048
  int n = blockIdx.y;                      // 96 (rows 69..95 zero-pad)
  float v = (n < IN) ? fc1w[(size_t)n * H + k] : 0.f;
  fc1b16[(size_t)n * H + k] = f2bf(v);
}

// ---------------- fused GRU step ----------------
// grid = 256 (XCD-swizzled -> (mt, ct)), block = 256 (4 waves).
// WG computes h'[m0:m0+64, c0:c0+64]. Wave w handles c-cols c0+16w..+16.
__global__ __launch_bounds__(256, 1) void gru_step(
    const ushort_t* __restrict__ Aprev, ushort_t* __restrict__ Anext,
    const ushort_t* __restrict__ Wbig, float* __restrict__ h32,
    const float* __restrict__ b_ih, const float* __restrict__ b_hh,
    const float* __restrict__ xsrc, int xstride)
{
  __shared__ __align__(16) ushort_t Alds[2][64 * 64];
  __shared__ __align__(16) ushort_t Blds[2][192 * 64];

  const int tid = threadIdx.x;
  const int bid = blockIdx.x;
  const int xcd = bid & 7, slot = bid >> 3;
  const int ct = xcd * 4 + (slot & 3);   // 0..31 : 4 c-tiles per XCD for L2 reuse
  const int mt = slot >> 2;              // 0..7
  const int m0 = mt * 64, c0 = ct * 64;
  const int lane = tid & 63, w = tid >> 6;
  const int l15 = lane & 15, l4 = lane >> 4;

  // hoisted staging sources (XOR-swizzle folded into the GLOBAL address; LDS stays linear)
  const ushort_t* srcA[2];
  const ushort_t* srcB[6];
  #pragma unroll
  for (int r = 0; r < 2; ++r) {
    int byte = r * 4096 + tid * 16;
    int row = byte >> 7, colb = byte & 127;
    int sc = colb ^ ((row & 7) << 4);
    srcA[r] = Aprev + (size_t)(m0 + row) * KP + (sc >> 1);
  }
  #pragma unroll
  for (int r = 0; r < 6; ++r) {
    int byte = r * 4096 + tid * 16;
    int row = byte >> 7, colb = byte & 127;
    int sc = colb ^ ((row & 7) << 4);
    srcB[r] = Wbig + (size_t)(ct * 256 + row) * KP + (sc >> 1);
  }

  // hoisted swizzled ds_read byte offsets (kt-independent)
  int offA[2][4], offB[2][3];
  #pragma unroll
  for (int kk = 0; kk < 2; ++kk) {
    int kbyte = kk * 64 + l4 * 16;
    #pragma unroll
    for (int mi = 0; mi < 4; ++mi) { int row = mi * 16 + l15; offA[kk][mi] = row * 128 + (kbyte ^ ((row & 7) << 4)); }
    #pragma unroll
    for (int ni = 0; ni < 3; ++ni) { int row = ni * 64 + w * 16 + l15; offB[kk][ni] = row * 128 + (kbyte ^ ((row & 7) << 4)); }
  }

  float4_t acc[4][4] = {};  // [mi][r,z,gh_n,gi_n]

  auto stage = [&](int kt, int buf) {
    const int kadv = kt * 64;
    #pragma unroll
    for (int r = 0; r < 2; ++r)
      gload_lds16(srcA[r] + kadv, (char*)&Alds[buf][0] + r * 4096 + w * 1024);
    const size_t nadj = (kt >= 32) ? (size_t)64 * KP : 0;  // swap g2 block -> g3 block
    #pragma unroll
    for (int r = 0; r < 6; ++r)
      gload_lds16(srcB[r] + kadv + (r >= 4 ? nadj : 0), (char*)&Blds[buf][0] + r * 4096 + w * 1024);
  };

  auto compute = [&](int kt, int buf) {
    const char* Ab = (const char*)&Alds[buf][0];
    const char* Bb = (const char*)&Blds[buf][0];
    #pragma unroll
    for (int kk = 0; kk < 2; ++kk) {
      short8 a[4], b[3];
      #pragma unroll
      for (int mi = 0; mi < 4; ++mi) a[mi] = *(const short8*)(Ab + offA[kk][mi]);
      #pragma unroll
      for (int ni = 0; ni < 3; ++ni) b[ni] = *(const short8*)(Bb + offB[kk][ni]);
      #pragma unroll
      for (int mi = 0; mi < 4; ++mi) {
        acc[mi][0] = __builtin_amdgcn_mfma_f32_16x16x32_bf16(a[mi], b[0], acc[mi][0], 0, 0, 0);
        acc[mi][1] = __builtin_amdgcn_mfma_f32_16x16x32_bf16(a[mi], b[1], acc[mi][1], 0, 0, 0);
        if (kt < 32)
          acc[mi][2] = __builtin_amdgcn_mfma_f32_16x16x32_bf16(a[mi], b[2], acc[mi][2], 0, 0, 0);
        else
          acc[mi][3] = __builtin_amdgcn_mfma_f32_16x16x32_bf16(a[mi], b[2], acc[mi][3], 0, 0, 0);
      }
    }
  };

  stage(0, 0);
  __syncthreads();
  int cur = 0;
  for (int kt = 0; kt < 34; ++kt) {
    if (kt < 33) stage(kt + 1, cur ^ 1);  // DMA overlaps this tile's compute
    compute(kt, cur);
    __syncthreads();                      // drains vmcnt(0): next buffer ready
    cur ^= 1;
  }

  // epilogue: gates in fp32, fp32 carry, dual h write
  const int c = c0 + w * 16 + l15;
  const float br  = b_ih[c] + b_hh[c];
  const float bz  = b_ih[H + c] + b_hh[H + c];
  const float bin = b_ih[2 * H + c];
  const float bhn = b_hh[2 * H + c];
  #pragma unroll
  for (int mi = 0; mi < 4; ++mi) {
    #pragma unroll
    for (int r4 = 0; r4 < 4; ++r4) {
      int m = m0 + mi * 16 + l4 * 4 + r4;
      float rg = 1.f / (1.f + __expf(-(acc[mi][0][r4] + br)));
      float zg = 1.f / (1.f + __expf(-(acc[mi][1][r4] + bz)));
      float ng = tanhf(acc[mi][3][r4] + bin + rg * (acc[mi][2][r4] + bhn));
      float hold = h32[(size_t)m * H + c];
      float hn = (1.f - zg) * ng + zg * hold;
      h32[(size_t)m * H + c] = hn;
      Anext[(size_t)m * KP + c] = f2bf(hn);
    }
  }
  // encoder next-x copy into the other parity (ct==0 WGs cover all 512 rows)
  if (ct == 0 && xsrc != nullptr) {
    for (int i = tid; i < 64 * IN; i += 256) {
      int rr = i / IN, cc = i - rr * IN;
      Anext[(size_t)(m0 + rr) * KP + H + cc] = f2bf(xsrc[(size_t)(m0 + rr) * xstride + cc]);
    }
  }
}

// ---------------- decoder output step ----------------
// out[m, j] = inp[m, j] + h_new[m,:] @ fc1_w[j,:] + fc1_b[j];  j<69, K=2048
// reads bf16 h from Acat (h region), writes d_out slice + next x (bf16) into same Acat.
__global__ __launch_bounds__(256, 1) void out_step(
    ushort_t* Acat,
    const ushort_t* __restrict__ fc1b16,   // [96][2048] bf16
    const float* __restrict__ fc1_bias,
    const float* __restrict__ inp,         // row stride TGT*IN
    float* __restrict__ outp)              // d_out + d*IN, row stride TGT*IN
{
  __shared__ __align__(16) ushort_t Alds[2][64 * 64];
  __shared__ __align__(16) ushort_t Blds[2][96 * 64];
  const int tid = threadIdx.x;
  const int m0 = blockIdx.x * 64;
  const int lane = tid & 63, w = tid >> 6, l15 = lane & 15, l4 = lane >> 4;

  const ushort_t* srcA[2]; const ushort_t* srcB[3];
  #pragma unroll
  for (int r = 0; r < 2; ++r) {
    int byte = r * 4096 + tid * 16; int row = byte >> 7, colb = byte & 127;
    int sc = colb ^ ((row & 7) << 4);
    srcA[r] = Acat + (size_t)(m0 + row) * KP + (sc >> 1);
  }
  #pragma unroll
  for (int r = 0; r < 3; ++r) {
    int byte = r * 4096 + tid * 16; int row = byte >> 7, colb = byte & 127;
    int sc = colb ^ ((row & 7) << 4);
    srcB[r] = fc1b16 + (size_t)row * H + (sc >> 1);
  }
  int offA[2], offB[2][5];
  #pragma unroll
  for (int kk = 0; kk < 2; ++kk) {
    int kbyte = kk * 64 + l4 * 16;
    { int row = w * 16 + l15; offA[kk] = row * 128 + (kbyte ^ ((row & 7) << 4)); }
    #pragma unroll
    for (int ni = 0; ni < 5; ++ni) { int row = ni * 16 + l15; offB[kk][ni] = row * 128 + (kbyte ^ ((row & 7) << 4)); }
  }

  float4_t acc[5] = {};
  auto stage = [&](int kt, int buf) {
    int kadv = kt * 64;
    #pragma unroll
    for (int r = 0; r < 2; ++r) gload_lds16(srcA[r] + kadv, (char*)&Alds[buf][0] + r * 4096 + w * 1024);
    #pragma unroll
    for (int r = 0; r < 3; ++r) gload_lds16(srcB[r] + kadv, (char*)&Blds[buf][0] + r * 4096 + w * 1024);
  };
  auto compute = [&](int buf) {
    const char* Ab = (const char*)&Alds[buf][0];
    const char* Bb = (const char*)&Blds[buf][0];
    #pragma unroll
    for (int kk = 0; kk < 2; ++kk) {
      short8 a = *(const short8*)(Ab + offA[kk]);
      #pragma unroll
      for (int ni = 0; ni < 5; ++ni) {
        short8 b = *(const short8*)(Bb + offB[kk][ni]);
        acc[ni] = __builtin_amdgcn_mfma_f32_16x16x32_bf16(a, b, acc[ni], 0, 0, 0);
      }
    }
  };

  stage(0, 0);
  __syncthreads();
  int cur = 0;
  for (int kt = 0; kt < 32; ++kt) {
    if (kt < 31) stage(kt + 1, cur ^ 1);
    compute(cur);
    __syncthreads();
    cur ^= 1;
  }

  #pragma unroll
  for (int ni = 0; ni < 5; ++ni) {
    int j = ni * 16 + l15;
    if (j < IN) {
      float bj = fc1_bias[j];
      #pragma unroll
      for (int r4 = 0; r4 < 4; ++r4) {
        int m = m0 + w * 16 + l4 * 4 + r4;
        float v = acc[ni][r4] + bj + inp[(size_t)m * (TGT * IN) + j];
        outp[(size_t)m * (TGT * IN) + j] = v;
        Acat[(size_t)m * KP + H + j] = f2bf(v);   // next decoder input
      }
    }
  }
}

// ---------------- launch ----------------
extern "C" void kernel_launch(void* const* d_in, const int* in_sizes, int n_in,
                              void* d_out, int out_size, void* d_ws, size_t ws_size,
                              hipStream_t stream) {
  const float* enc  = (const float*)d_in[0];
  const float* dec  = (const float*)d_in[1];
  const float* Wih  = (const float*)d_in[2];
  const float* Whh  = (const float*)d_in[3];
  const float* b_ih = (const float*)d_in[4];
  const float* b_hh = (const float*)d_in[5];
  const float* fc1w = (const float*)d_in[6];
  const float* fc1b = (const float*)d_in[7];
  float* out = (float*)d_out;

  char* ws = (char*)d_ws;
  ushort_t* Wbig   = (ushort_t*)(ws);                 // 8192*2176*2 = 35,651,584
  ushort_t* Acat0  = (ushort_t*)(ws + 35651584);      // 512*2176*2  =  2,228,224
  ushort_t* Acat1  = (ushort_t*)(ws + 37879808);      // 512*2176*2
  float*    h32    = (float*)   (ws + 40108032);      // 512*2048*4  =  4,194,304
  ushort_t* fc1b16 = (ushort_t*)(ws + 44302336);      // 96*2048*2   =    393,216
  ushort_t* Acat[2] = {Acat0, Acat1};

  build_wbig<<<dim3(9, 8192), 256, 0, stream>>>(Whh, Wih, Wbig);
  zero_u4<<<2112, 256, 0, stream>>>((uint4*)Acat0, 540672);  // Acat0+Acat1+h32
  fill_x0<<<138, 256, 0, stream>>>(enc, Acat0);
  build_fc1<<<dim3(8, 96), 256, 0, stream>>>(fc1w, fc1b16);

  for (int t = 0; t < 149; ++t) {
    const float* xsrc = nullptr; int xstride = 0;
    if (t < 98)       { xsrc = enc + (size_t)(t + 1) * IN; xstride = 100 * IN; }
    else if (t == 98) { xsrc = dec;                        xstride = TGT * IN; }
    gru_step<<<256, 256, 0, stream>>>(Acat[t & 1], Acat[(t + 1) & 1], Wbig, h32,
                                      b_ih, b_hh, xsrc, xstride);
    if (t >= 99) {
      int d = t - 99;
      const float* inp = (d == 0) ? dec : out + (size_t)(d - 1) * IN;
      out_step<<<8, 256, 0, stream>>>(Acat[(t + 1) & 1], fc1b16, fc1b, inp,
                                      out + (size_t)d * IN);
    }
  }
}

// Round 2
// 4274.797 us; speedup vs baseline: 2.0537x; 2.0537x over previous
//
#include <hip/hip_runtime.h>

#define KP   2176   // padded K: 2048 h + 69 x + pad
#define H    2048
#define MB   512    // batch
#define IN   69
#define TGT  50

typedef unsigned short ushort_t;
typedef __attribute__((ext_vector_type(8))) short  short8;
typedef __attribute__((ext_vector_type(4))) float  float4_t;

__device__ __forceinline__ ushort_t f2bf(float f) {
  union { float f; unsigned u; } v; v.f = f;
  unsigned u = v.u;
  return (ushort_t)((u + 0x7fffu + ((u >> 16) & 1u)) >> 16);
}

__device__ __forceinline__ void gload_lds16(const void* g, void* l) {
  __builtin_amdgcn_global_load_lds((const __attribute__((address_space(1))) void*)g,
                                   (__attribute__((address_space(3))) void*)l, 16, 0, 0);
}

template <int N> __device__ __forceinline__ void waitv() {
  asm volatile("s_waitcnt vmcnt(%0)" :: "n"(N) : "memory");
}

// ---------------- prep kernels ----------------

// Compact W_big[6144][KP] bf16. n = ct*192 + g*64 + c64; c = ct*64 + c64; gate row gr = g*2048 + c.
// Every row is the fused [W_hh[gr] (k<2048) | W_ih[gr] (2048<=k<2117) | 0] pattern.
// g2's h-part (k<2048) feeds acc[2] (gh_n); g2's x-part (k>=2048) feeds acc[3] (gi_n)
// — selected by K-tile index in the GEMM, not by layout.
__global__ void build_wbig(const float* __restrict__ Whh, const float* __restrict__ Wih,
                           ushort_t* __restrict__ Wbig) {
  int k = blockIdx.x * 256 + threadIdx.x;
  int n = blockIdx.y;           // 0..6143
  if (k >= KP) return;
  int g = (n >> 6) % 3;
  int c = (n / 192) * 64 + (n & 63);
  int gr = g * H + c;
  float v = 0.f;
  if (k < H) v = Whh[(size_t)gr * H + k];
  else if (k < H + IN) v = Wih[(size_t)gr * IN + (k - H)];
  Wbig[(size_t)n * KP + k] = f2bf(v);
}

__global__ void zero_u4(uint4* p, int n) {
  int i = blockIdx.x * 256 + threadIdx.x;
  if (i < n) p[i] = make_uint4(0, 0, 0, 0);
}

__global__ void fill_x0(const float* __restrict__ enc, ushort_t* __restrict__ Acat0) {
  int i = blockIdx.x * 256 + threadIdx.x;  // exactly 512*69 threads
  int b = i / IN, j = i - b * IN;
  Acat0[(size_t)b * KP + H + j] = f2bf(enc[(size_t)b * 100 * IN + j]);
}

__global__ void build_fc1(const float* __restrict__ fc1w, ushort_t* __restrict__ fc1b16) {
  int k = blockIdx.x * 256 + threadIdx.x;  // 2048
  int n = blockIdx.y;                      // 96 (rows 69..95 zero-pad)
  float v = (n < IN) ? fc1w[(size_t)n * H + k] : 0.f;
  fc1b16[(size_t)n * H + k] = f2bf(v);
}

// ---------------- fused GRU step ----------------
// grid = 256 (XCD-swizzled -> (mt, ct)), block = 256 (4 waves).
// Ring-4 LDS pipeline with counted vmcnt (T3+T4): never drain to 0 in the loop.
__global__ __launch_bounds__(256, 1) void gru_step(
    const ushort_t* __restrict__ Aprev, ushort_t* __restrict__ Anext,
    const ushort_t* __restrict__ Wbig, float* __restrict__ h32,
    const float* __restrict__ b_ih, const float* __restrict__ b_hh,
    const float* __restrict__ xsrc, int xstride)
{
  // ring of 4 buffers: per buffer A 8KB @0, B 24KB @8192  (4*32KB = 128KB LDS)
  __shared__ __align__(16) char lds[4][32768];

  const int tid = threadIdx.x;
  const int bid = blockIdx.x;
  const int xcd = bid & 7, slot = bid >> 3;
  const int ct = xcd * 4 + (slot & 3);   // 0..31 : 4 c-tiles per XCD for L2 reuse
  const int mt = slot >> 2;              // 0..7
  const int m0 = mt * 64, c0 = ct * 64;
  const int lane = tid & 63, w = tid >> 6;
  const int l15 = lane & 15, l4 = lane >> 4;

  // staging sources (XOR-swizzle folded into the GLOBAL address; LDS stays linear)
  const ushort_t* srcA[2];
  const ushort_t* srcB[6];
  #pragma unroll
  for (int r = 0; r < 2; ++r) {
    int byte = r * 4096 + tid * 16;
    int row = byte >> 7, colb = byte & 127;
    int sc = colb ^ ((row & 7) << 4);
    srcA[r] = Aprev + (size_t)(m0 + row) * KP + (sc >> 1);
  }
  #pragma unroll
  for (int r = 0; r < 6; ++r) {
    int byte = r * 4096 + tid * 16;
    int row = byte >> 7, colb = byte & 127;
    int sc = colb ^ ((row & 7) << 4);
    srcB[r] = Wbig + (size_t)(ct * 192 + row) * KP + (sc >> 1);
  }

  // swizzled ds_read byte offsets (buffer-relative, kt-independent)
  int offA[2][4], offB[2][3];
  #pragma unroll
  for (int kk = 0; kk < 2; ++kk) {
    int kbyte = kk * 64 + l4 * 16;
    #pragma unroll
    for (int mi = 0; mi < 4; ++mi) { int row = mi * 16 + l15; offA[kk][mi] = row * 128 + (kbyte ^ ((row & 7) << 4)); }
    #pragma unroll
    for (int ni = 0; ni < 3; ++ni) { int row = ni * 64 + w * 16 + l15; offB[kk][ni] = row * 128 + (kbyte ^ ((row & 7) << 4)); }
  }

  float4_t acc[4][4] = {};  // [mi][r,z,gh_n,gi_n]

  auto stage = [&](int kt, int buf) {
    const int kadv = kt * 64;
    char* base = &lds[0][0] + buf * 32768;
    #pragma unroll
    for (int r = 0; r < 2; ++r)
      gload_lds16(srcA[r] + kadv, base + r * 4096 + w * 1024);
    #pragma unroll
    for (int r = 0; r < 6; ++r)
      gload_lds16(srcB[r] + kadv, base + 8192 + r * 4096 + w * 1024);
  };

  auto compute = [&](int buf, bool g3) {
    const char* Ab = (const char*)&lds[0][0] + buf * 32768;
    const char* Bb = Ab + 8192;
    #pragma unroll
    for (int kk = 0; kk < 2; ++kk) {
      short8 a[4], b[3];
      #pragma unroll
      for (int mi = 0; mi < 4; ++mi) a[mi] = *(const short8*)(Ab + offA[kk][mi]);
      #pragma unroll
      for (int ni = 0; ni < 3; ++ni) b[ni] = *(const short8*)(Bb + offB[kk][ni]);
      #pragma unroll
      for (int mi = 0; mi < 4; ++mi) {
        acc[mi][0] = __builtin_amdgcn_mfma_f32_16x16x32_bf16(a[mi], b[0], acc[mi][0], 0, 0, 0);
        acc[mi][1] = __builtin_amdgcn_mfma_f32_16x16x32_bf16(a[mi], b[1], acc[mi][1], 0, 0, 0);
        if (!g3)
          acc[mi][2] = __builtin_amdgcn_mfma_f32_16x16x32_bf16(a[mi], b[2], acc[mi][2], 0, 0, 0);
        else
          acc[mi][3] = __builtin_amdgcn_mfma_f32_16x16x32_bf16(a[mi], b[2], acc[mi][3], 0, 0, 0);
      }
    }
  };

  #define BAR() __builtin_amdgcn_s_barrier()

  stage(0, 0); stage(1, 1); stage(2, 2);
  // steady state: {wait own stage(kt) retired (2 stages remain in flight); barrier
  //  (=> ALL waves' stage(kt) retired); compute(kt); stage(kt+3) overwrites buf[kt-1],
  //  whose readers all passed this barrier}.
  for (int kt = 0; kt < 28; kt += 4) {
    waitv<16>(); BAR(); compute(0, false); stage(kt + 3, 3);
    waitv<16>(); BAR(); compute(1, false); stage(kt + 4, 0);
    waitv<16>(); BAR(); compute(2, false); stage(kt + 5, 1);
    waitv<16>(); BAR(); compute(3, false); stage(kt + 6, 2);
  }
  waitv<16>(); BAR(); compute(0, false); stage(31, 3);   // kt=28
  waitv<16>(); BAR(); compute(1, false); stage(32, 0);   // kt=29
  waitv<16>(); BAR(); compute(2, false); stage(33, 1);   // kt=30
  waitv<16>(); BAR(); compute(3, false);                 // kt=31
  waitv<8>();  BAR(); compute(0, true);                  // kt=32 (x-part -> gi_n)
  waitv<0>();  BAR(); compute(1, true);                  // kt=33

  // epilogue: gates in fp32, fp32 carry, dual h write
  const int c = c0 + w * 16 + l15;
  const float br  = b_ih[c] + b_hh[c];
  const float bz  = b_ih[H + c] + b_hh[H + c];
  const float bin = b_ih[2 * H + c];
  const float bhn = b_hh[2 * H + c];
  #pragma unroll
  for (int mi = 0; mi < 4; ++mi) {
    #pragma unroll
    for (int r4 = 0; r4 < 4; ++r4) {
      int m = m0 + mi * 16 + l4 * 4 + r4;
      float rg = 1.f / (1.f + __expf(-(acc[mi][0][r4] + br)));
      float zg = 1.f / (1.f + __expf(-(acc[mi][1][r4] + bz)));
      float ng = tanhf(acc[mi][3][r4] + bin + rg * (acc[mi][2][r4] + bhn));
      float hold = h32[(size_t)m * H + c];
      float hn = (1.f - zg) * ng + zg * hold;
      h32[(size_t)m * H + c] = hn;
      Anext[(size_t)m * KP + c] = f2bf(hn);
    }
  }
  // encoder next-x copy into the other parity (ct==0 WGs cover all 512 rows)
  if (ct == 0 && xsrc != nullptr) {
    for (int i = tid; i < 64 * IN; i += 256) {
      int rr = i / IN, cc = i - rr * IN;
      Anext[(size_t)(m0 + rr) * KP + H + cc] = f2bf(xsrc[(size_t)(m0 + rr) * xstride + cc]);
    }
  }
}

// ---------------- decoder output step ----------------
// out[m, j] = inp[m, j] + h_new[m,:] @ fc1_w[j,:] + fc1_b[j];  j<69, K=2048
__global__ __launch_bounds__(256, 1) void out_step(
    ushort_t* Acat,
    const ushort_t* __restrict__ fc1b16,   // [96][2048] bf16
    const float* __restrict__ fc1_bias,
    const float* __restrict__ inp,         // row stride TGT*IN
    float* __restrict__ outp)              // d_out + d*IN, row stride TGT*IN
{
  // ring of 4 buffers: per buffer A 8KB @0, B 12KB @8192  (4*20KB = 80KB LDS)
  __shared__ __align__(16) char lds[4][20480];
  const int tid = threadIdx.x;
  const int m0 = blockIdx.x * 64;
  const int lane = tid & 63, w = tid >> 6, l15 = lane & 15, l4 = lane >> 4;

  const ushort_t* srcA[2]; const ushort_t* srcB[3];
  #pragma unroll
  for (int r = 0; r < 2; ++r) {
    int byte = r * 4096 + tid * 16; int row = byte >> 7, colb = byte & 127;
    int sc = colb ^ ((row & 7) << 4);
    srcA[r] = Acat + (size_t)(m0 + row) * KP + (sc >> 1);
  }
  #pragma unroll
  for (int r = 0; r < 3; ++r) {
    int byte = r * 4096 + tid * 16; int row = byte >> 7, colb = byte & 127;
    int sc = colb ^ ((row & 7) << 4);
    srcB[r] = fc1b16 + (size_t)row * H + (sc >> 1);
  }
  int offA[2], offB[2][5];
  #pragma unroll
  for (int kk = 0; kk < 2; ++kk) {
    int kbyte = kk * 64 + l4 * 16;
    { int row = w * 16 + l15; offA[kk] = row * 128 + (kbyte ^ ((row & 7) << 4)); }
    #pragma unroll
    for (int ni = 0; ni < 5; ++ni) { int row = ni * 16 + l15; offB[kk][ni] = row * 128 + (kbyte ^ ((row & 7) << 4)); }
  }

  float4_t acc[5] = {};
  auto stage = [&](int kt, int buf) {
    int kadv = kt * 64;
    char* base = &lds[0][0] + buf * 20480;
    #pragma unroll
    for (int r = 0; r < 2; ++r) gload_lds16(srcA[r] + kadv, base + r * 4096 + w * 1024);
    #pragma unroll
    for (int r = 0; r < 3; ++r) gload_lds16(srcB[r] + kadv, base + 8192 + r * 4096 + w * 1024);
  };
  auto compute = [&](int buf) {
    const char* Ab = (const char*)&lds[0][0] + buf * 20480;
    const char* Bb = Ab + 8192;
    #pragma unroll
    for (int kk = 0; kk < 2; ++kk) {
      short8 a = *(const short8*)(Ab + offA[kk]);
      #pragma unroll
      for (int ni = 0; ni < 5; ++ni) {
        short8 b = *(const short8*)(Bb + offB[kk][ni]);
        acc[ni] = __builtin_amdgcn_mfma_f32_16x16x32_bf16(a, b, acc[ni], 0, 0, 0);
      }
    }
  };

  stage(0, 0); stage(1, 1); stage(2, 2);
  for (int kt = 0; kt < 28; kt += 4) {
    waitv<10>(); BAR(); compute(0); stage(kt + 3, 3);
    waitv<10>(); BAR(); compute(1); stage(kt + 4, 0);
    waitv<10>(); BAR(); compute(2); stage(kt + 5, 1);
    waitv<10>(); BAR(); compute(3); stage(kt + 6, 2);
  }
  waitv<10>(); BAR(); compute(0); stage(31, 3);  // kt=28
  waitv<10>(); BAR(); compute(1);                // kt=29
  waitv<5>();  BAR(); compute(2);                // kt=30
  waitv<0>();  BAR(); compute(3);                // kt=31

  #pragma unroll
  for (int ni = 0; ni < 5; ++ni) {
    int j = ni * 16 + l15;
    if (j < IN) {
      float bj = fc1_bias[j];
      #pragma unroll
      for (int r4 = 0; r4 < 4; ++r4) {
        int m = m0 + w * 16 + l4 * 4 + r4;
        float v = acc[ni][r4] + bj + inp[(size_t)m * (TGT * IN) + j];
        outp[(size_t)m * (TGT * IN) + j] = v;
        Acat[(size_t)m * KP + H + j] = f2bf(v);   // next decoder input
      }
    }
  }
}

// ---------------- launch ----------------
extern "C" void kernel_launch(void* const* d_in, const int* in_sizes, int n_in,
                              void* d_out, int out_size, void* d_ws, size_t ws_size,
                              hipStream_t stream) {
  const float* enc  = (const float*)d_in[0];
  const float* dec  = (const float*)d_in[1];
  const float* Wih  = (const float*)d_in[2];
  const float* Whh  = (const float*)d_in[3];
  const float* b_ih = (const float*)d_in[4];
  const float* b_hh = (const float*)d_in[5];
  const float* fc1w = (const float*)d_in[6];
  const float* fc1b = (const float*)d_in[7];
  float* out = (float*)d_out;

  char* ws = (char*)d_ws;
  ushort_t* Wbig   = (ushort_t*)(ws);                 // 6144*2176*2 = 26,738,688
  ushort_t* Acat0  = (ushort_t*)(ws + 26738688);      // 512*2176*2  =  2,228,224
  ushort_t* Acat1  = (ushort_t*)(ws + 28966912);      // 512*2176*2
  float*    h32    = (float*)   (ws + 31195136);      // 512*2048*4  =  4,194,304
  ushort_t* fc1b16 = (ushort_t*)(ws + 35389440);      // 96*2048*2   =    393,216
  ushort_t* Acat[2] = {Acat0, Acat1};

  build_wbig<<<dim3(9, 6144), 256, 0, stream>>>(Whh, Wih, Wbig);
  zero_u4<<<2112, 256, 0, stream>>>((uint4*)Acat0, 540672);  // Acat0+Acat1+h32
  fill_x0<<<138, 256, 0, stream>>>(enc, Acat0);
  build_fc1<<<dim3(8, 96), 256, 0, stream>>>(fc1w, fc1b16);

  for (int t = 0; t < 149; ++t) {
    const float* xsrc = nullptr; int xstride = 0;
    if (t < 98)       { xsrc = enc + (size_t)(t + 1) * IN; xstride = 100 * IN; }
    else if (t == 98) { xsrc = dec;                        xstride = TGT * IN; }
    gru_step<<<256, 256, 0, stream>>>(Acat[t & 1], Acat[(t + 1) & 1], Wbig, h32,
                                      b_ih, b_hh, xsrc, xstride);
    if (t >= 99) {
      int d = t - 99;
      const float* inp = (d == 0) ? dec : out + (size_t)(d - 1) * IN;
      out_step<<<8, 256, 0, stream>>>(Acat[(t + 1) & 1], fc1b16, fc1b, inp,
                                      out + (size_t)d * IN);
    }
  }
}